// Round 1
// baseline (46.483 us; speedup 1.0000x reference)
//
#include <hip/hip_runtime.h>

#define NROWS 8192
#define DIM   256          // elements per row == bytes per row in fp8
#define BHALF 4096
#define NTILE 64           // 8192 / 128
#define BM    128
#define BK    128          // K-bytes per phase (2 phases cover K=256)
#define SQRT2 1.41421356237f

typedef unsigned char u8;
typedef __attribute__((ext_vector_type(4))) float f32x4;
typedef __attribute__((ext_vector_type(4))) int   i32x4;
typedef __attribute__((ext_vector_type(8))) int   i32x8;

__device__ inline void gload_lds16(const void* g, void* l) {
  __builtin_amdgcn_global_load_lds(
      (const __attribute__((address_space(1))) void*)g,
      (__attribute__((address_space(3))) void*)l, 16, 0, 0);
}

// Kernel 1: row-normalize concat(z_i, z_j), scale by sqrt(2) so dot = cos/TEMP,
// emit fp8 e4m3 Zn8 [8192][256] (2 MB; fits in each XCD's 4MB L2).
// Also zeroes the output scalar (stream-ordered before fin's atomics).
__global__ __launch_bounds__(256) void nrm_kernel(const float* __restrict__ zi,
                                                  const float* __restrict__ zj,
                                                  u8* __restrict__ zn8,
                                                  float* __restrict__ out) {
  if (blockIdx.x == 0 && threadIdx.x == 0) out[0] = 0.f;
  const int w = threadIdx.x >> 6, l = threadIdx.x & 63;
  const int row = blockIdx.x * 4 + w;
  const float* src = (row < BHALF) ? zi + (size_t)row * DIM
                                   : zj + (size_t)(row - BHALF) * DIM;
  float4 v = *(const float4*)(src + l * 4);
  float ss = v.x * v.x + v.y * v.y + v.z * v.z + v.w * v.w;
#pragma unroll
  for (int m = 1; m < 64; m <<= 1) ss += __shfl_xor(ss, m);
  float inv = SQRT2 / fmaxf(sqrtf(ss), 1e-8f);
  int p = __builtin_amdgcn_cvt_pk_fp8_f32(v.x * inv, v.y * inv, 0, false);
  p = __builtin_amdgcn_cvt_pk_fp8_f32(v.z * inv, v.w * inv, p, true);
  *(int*)(zn8 + (size_t)row * DIM + (size_t)l * 4) = p;
}

// Kernel 2: upper-triangle 128x128 Gram tiles, MX-scaled fp8 MFMA (K=128,
// unit e8m0 scales -> exact fp8 matmul at 2.28x the non-scaled rate).
// 2 K-phases, both staged up front; counted vmcnt (phase 0 computes while
// phase 1's 8 loads stay in flight); ONE raw s_barrier per phase.
// 66.5 KB LDS -> 2 blocks/CU.
__global__ __launch_bounds__(256, 2) void sim_kernel(const u8* __restrict__ zn8,
                                                     float* __restrict__ partials,
                                                     float* __restrict__ pos) {
  __shared__ __align__(16) u8 Asm[2][BM * BK];   // 2 x 16 KB
  __shared__ __align__(16) u8 Bsm[2][BM * BK];   // 2 x 16 KB
  __shared__ float brs_r[BM];
  __shared__ float brs_c[BM];

  const int t = threadIdx.x;
  const int w = t >> 6, l = t & 63;
  const int wr = w >> 1, wc = w & 1;
  const int rl = l & 15, kg = l >> 4;   // kg selects this lane's 32B k-block

  // blockIdx -> upper triangle (rt <= ct), row-major enumeration
  const int bid = blockIdx.x;
  int rt = (int)((129.0f - sqrtf(129.0f * 129.0f - 8.0f * (float)bid)) * 0.5f);
  while (NTILE * rt - rt * (rt - 1) / 2 > bid) --rt;
  while (NTILE * (rt + 1) - (rt + 1) * rt / 2 <= bid) ++rt;
  const int ct = rt + (bid - (NTILE * rt - rt * (rt - 1) / 2));
  const int rowbase = rt * BM, colbase = ct * BM;

  if (t < BM) { brs_r[t] = 0.f; brs_c[t] = 0.f; }

  // stage phase p: 16 KB each of A,B = 1024 16B-chunks each; 4 iters x 2 loads.
  // dest linear (gload_lds writes base+lane*16); source chunk inverse-swizzled
  // with salt (row & 7) so ds_read_b128 hits the 8-per-bank-quad floor.
  auto STAGE = [&](int p) {
#pragma unroll
    for (int i = 0; i < 4; ++i) {
      int chunk = i * 256 + t;          // 0..1023
      int r = chunk >> 3, cd = chunk & 7;
      int cs = cd ^ (r & 7);
      size_t gofs = (size_t)(p * BK + cs * 16);
      gload_lds16(zn8 + (size_t)(rowbase + r) * DIM + gofs,
                  (u8*)&Asm[p][0] + (size_t)((i * 256 + w * 64) * 16));
      gload_lds16(zn8 + (size_t)(colbase + r) * DIM + gofs,
                  (u8*)&Bsm[p][0] + (size_t)((i * 256 + w * 64) * 16));
    }
  };

  f32x4 acc[4][4];
#pragma unroll
  for (int i = 0; i < 4; ++i)
#pragma unroll
    for (int j = 0; j < 4; ++j) acc[i][j] = (f32x4){0.f, 0.f, 0.f, 0.f};

  // per-fragment read bases (swizzle salt depends on row only)
  int abase[4], asw[4], bbase[4], bsw[4];
#pragma unroll
  for (int mi = 0; mi < 4; ++mi) {
    int ra = wr * 64 + mi * 16 + rl;
    abase[mi] = ra * BK; asw[mi] = ra & 7;
    int rb = wc * 64 + mi * 16 + rl;
    bbase[mi] = rb * BK; bsw[mi] = rb & 7;
  }

  STAGE(0);                 // 8 loads in flight
  STAGE(1);                 // 16 in flight

#pragma unroll
  for (int p = 0; p < 2; ++p) {
    // phase p's 8 loads complete (phase 1's 8 may remain in flight at p=0)
    if (p == 0) asm volatile("s_waitcnt vmcnt(8)" ::: "memory");
    else        asm volatile("s_waitcnt vmcnt(0)" ::: "memory");
    __builtin_amdgcn_sched_barrier(0);
    __builtin_amdgcn_s_barrier();    // all waves' loads for phase p done
    __builtin_amdgcn_sched_barrier(0);

    const u8* Ab = &Asm[p][0];
    const u8* Bb = &Bsm[p][0];
    i32x8 a[4], b[4];
#pragma unroll
    for (int mi = 0; mi < 4; ++mi) {
      const int c0 = (kg * 2) ^ asw[mi];       // 16B chunk of lane's 32B block
      const int c1 = (kg * 2 + 1) ^ asw[mi];
      i32x4 lo = *(const i32x4*)(Ab + abase[mi] + (c0 << 4));
      i32x4 hi = *(const i32x4*)(Ab + abase[mi] + (c1 << 4));
      a[mi] = __builtin_shufflevector(lo, hi, 0, 1, 2, 3, 4, 5, 6, 7);
    }
#pragma unroll
    for (int ni = 0; ni < 4; ++ni) {
      const int c0 = (kg * 2) ^ bsw[ni];
      const int c1 = (kg * 2 + 1) ^ bsw[ni];
      i32x4 lo = *(const i32x4*)(Bb + bbase[ni] + (c0 << 4));
      i32x4 hi = *(const i32x4*)(Bb + bbase[ni] + (c1 << 4));
      b[ni] = __builtin_shufflevector(lo, hi, 0, 1, 2, 3, 4, 5, 6, 7);
    }
#pragma unroll
    for (int mi = 0; mi < 4; ++mi)
#pragma unroll
      for (int ni = 0; ni < 4; ++ni)
        acc[mi][ni] = __builtin_amdgcn_mfma_scale_f32_16x16x128_f8f6f4(
            a[mi], b[ni], acc[mi][ni],
            0, 0,                      // cbsz=fp8, blgp=fp8
            0, 0x7f7f7f7f,             // opsel_a, scale_a = 1.0 (e8m0 127)
            0, 0x7f7f7f7f);            // opsel_b, scale_b = 1.0
  }

  // ---- epilogue: exp once, accumulate row-sums AND col-sums ----
  const int colg = l & 15, rowg = l >> 4;

  if (ct == rt + 32) {   // only these tiles contain positive pairs
#pragma unroll
    for (int mi = 0; mi < 4; ++mi)
#pragma unroll
      for (int j = 0; j < 4; ++j) {
        const int R = rowbase + wr * 64 + mi * 16 + rowg * 4 + j;
#pragma unroll
        for (int ni = 0; ni < 4; ++ni) {
          const int C = colbase + wc * 64 + ni * 16 + colg;
          if (C == R + BHALF) {
            float v = acc[mi][ni][j];
            pos[R] = v; pos[C] = v;
          }
        }
      }
  }

  float csum[4] = {0.f, 0.f, 0.f, 0.f};
  if (rt == ct) {   // diagonal tiles: exclude C==R
#pragma unroll
    for (int mi = 0; mi < 4; ++mi)
#pragma unroll
      for (int j = 0; j < 4; ++j) {
        const int R = rowbase + wr * 64 + mi * 16 + rowg * 4 + j;
        float s = 0.f;
#pragma unroll
        for (int ni = 0; ni < 4; ++ni) {
          const int C = colbase + wc * 64 + ni * 16 + colg;
          float e = (C != R) ? __expf(acc[mi][ni][j]) : 0.f;
          s += e; csum[ni] += e;
        }
        s += __shfl_xor(s, 1); s += __shfl_xor(s, 2);
        s += __shfl_xor(s, 4); s += __shfl_xor(s, 8);
        if (colg == 0)
          atomicAdd(&brs_r[wr * 64 + mi * 16 + rowg * 4 + j], s);
      }
  } else {          // fast path: no masks
#pragma unroll
    for (int mi = 0; mi < 4; ++mi)
#pragma unroll
      for (int j = 0; j < 4; ++j) {
        float s = 0.f;
#pragma unroll
        for (int ni = 0; ni < 4; ++ni) {
          float e = __expf(acc[mi][ni][j]);
          s += e; csum[ni] += e;
        }
        s += __shfl_xor(s, 1); s += __shfl_xor(s, 2);
        s += __shfl_xor(s, 4); s += __shfl_xor(s, 8);
        if (colg == 0)
          atomicAdd(&brs_r[wr * 64 + mi * 16 + rowg * 4 + j], s);
      }
  }
  // col-sums: reduce over the 4 row-lane groups (xor bits 4..5)
#pragma unroll
  for (int ni = 0; ni < 4; ++ni) {
    float cs = csum[ni];
    cs += __shfl_xor(cs, 16); cs += __shfl_xor(cs, 32);
    if (rowg == 0)
      atomicAdd(&brs_c[wc * 64 + ni * 16 + colg], cs);
  }
  __syncthreads();
  if (t < BM) {
    partials[(size_t)ct * NROWS + rowbase + t] = brs_r[t];
    if (rt != ct)
      partials[(size_t)rt * NROWS + colbase + t] = brs_c[t];
  }
}

// Kernel 3: per-row lse - pos; per-block sums folded into one global atomic
// (out pre-zeroed by nrm_kernel; stream order guarantees visibility).
__global__ __launch_bounds__(256) void fin_kernel(const float* __restrict__ partials,
                                                  const float* __restrict__ pos,
                                                  float* __restrict__ out) {
  const int r = blockIdx.x * 256 + threadIdx.x;
  float s = 0.f;
#pragma unroll 8
  for (int ct = 0; ct < NTILE; ++ct) s += partials[(size_t)ct * NROWS + r];
  float v = logf(s) - pos[r];
#pragma unroll
  for (int m = 1; m < 64; m <<= 1) v += __shfl_xor(v, m);
  __shared__ float wsum[4];
  const int w = threadIdx.x >> 6, l = threadIdx.x & 63;
  if (l == 0) wsum[w] = v;
  __syncthreads();
  if (threadIdx.x == 0)
    atomicAdd(out, (wsum[0] + wsum[1] + wsum[2] + wsum[3]) * (1.f / NROWS));
}

extern "C" void kernel_launch(void* const* d_in, const int* in_sizes, int n_in,
                              void* d_out, int out_size, void* d_ws, size_t ws_size,
                              hipStream_t stream) {
  const float* zi = (const float*)d_in[0];
  const float* zj = (const float*)d_in[1];

  u8*    zn8      = (u8*)d_ws;                                             // 2 MB
  float* partials = (float*)((char*)d_ws + (size_t)NROWS * DIM);           // 2 MB
  float* pos      = (float*)((char*)partials + (size_t)NTILE * NROWS * 4); // 32 KB
  float* out      = (float*)d_out;

  nrm_kernel<<<NROWS / 4, 256, 0, stream>>>(zi, zj, zn8, out);
  sim_kernel<<<NTILE * (NTILE + 1) / 2, 256, 0, stream>>>(zn8, partials, pos);
  fin_kernel<<<NROWS / 256, 256, 0, stream>>>(partials, pos, out);
}